// Round 4
// baseline (277.752 us; speedup 1.0000x reference)
//
#include <hip/hip_runtime.h>
#include <math.h>

#define B_ 128
#define H_ 4
#define S_ 1024
#define M_ 256

typedef float vfloat4 __attribute__((ext_vector_type(4)));

// ---------------- helpers ----------------

__device__ __forceinline__ float wred_sum(float v) {
    #pragma unroll
    for (int o = 32; o; o >>= 1) v += __shfl_xor(v, o);
    return v;
}

__device__ __forceinline__ float wred_max(float v) {
    #pragma unroll
    for (int o = 32; o; o >>= 1) v = fmaxf(v, __shfl_xor(v, o));
    return v;
}

__device__ __forceinline__ float block_sum(float v, float* sbuf) {
    v = wred_sum(v);
    int wave = threadIdx.x >> 6, lane = threadIdx.x & 63;
    if (lane == 0) sbuf[wave] = v;
    __syncthreads();
    float r = sbuf[0] + sbuf[1] + sbuf[2] + sbuf[3];
    __syncthreads();
    return r;
}

__device__ __forceinline__ float block_max(float v, float* sbuf) {
    v = wred_max(v);
    int wave = threadIdx.x >> 6, lane = threadIdx.x & 63;
    if (lane == 0) sbuf[wave] = v;
    __syncthreads();
    float r = fmaxf(fmaxf(sbuf[0], sbuf[1]), fmaxf(sbuf[2], sbuf[3]));
    __syncthreads();
    return r;
}

// ---------------- K1: dots + row norms ----------------
// 16 lanes per row, 4 rows per wave-iter. grid: B*16 blocks, 64 rows/block.
// Regular (caching) loads: seeds L2/L3 with `memory` for K3's re-read.
__global__ __launch_bounds__(256) void k1_dots(
        const float* __restrict__ memory, const float* __restrict__ k,
        float* __restrict__ dots, float* __restrict__ mn) {
    const int RPB = 64;
    int bid = blockIdx.x;
    int b = bid / (S_ / RPB);
    int ch = bid % (S_ / RPB);
    int wave = threadIdx.x >> 6, lane = threadIdx.x & 63;
    int sub = lane & 15, rq = lane >> 4;

    float4 kf[H_][4];
    #pragma unroll
    for (int h = 0; h < H_; ++h)
        #pragma unroll
        for (int c = 0; c < 4; ++c)
            kf[h][c] = reinterpret_cast<const float4*>(
                k + ((size_t)b * H_ + h) * M_)[c * 16 + sub];

    #pragma unroll
    for (int i = 0; i < RPB / 16; ++i) {
        int s = ch * RPB + wave * 16 + i * 4 + rq;
        const float4* row = reinterpret_cast<const float4*>(
            memory + ((size_t)b * S_ + s) * M_);
        float d[H_] = {0.f, 0.f, 0.f, 0.f};
        float nn = 0.f;
        #pragma unroll
        for (int c = 0; c < 4; ++c) {
            float4 m4 = row[c * 16 + sub];
            #pragma unroll
            for (int h = 0; h < H_; ++h)
                d[h] += m4.x * kf[h][c].x + m4.y * kf[h][c].y
                      + m4.z * kf[h][c].z + m4.w * kf[h][c].w;
            nn += m4.x * m4.x + m4.y * m4.y + m4.z * m4.z + m4.w * m4.w;
        }
        #pragma unroll
        for (int o = 1; o < 16; o <<= 1) {
            #pragma unroll
            for (int h = 0; h < H_; ++h) d[h] += __shfl_xor(d[h], o);
            nn += __shfl_xor(nn, o);
        }
        if (sub == 0) {
            #pragma unroll
            for (int h = 0; h < H_; ++h)
                dots[((size_t)b * H_ + h) * S_ + s] = d[h];
            mn[(size_t)b * S_ + s] = sqrtf(nn);
        }
    }
}

// ---------------- K2: per-(b,h) weight pipeline ----------------
__global__ __launch_bounds__(256) void k2_weights(
        const float* __restrict__ k, const float* __restrict__ beta,
        const float* __restrict__ pw, const float* __restrict__ g,
        const float* __restrict__ sshift, const float* __restrict__ gamma,
        const float* __restrict__ dots, const float* __restrict__ mn,
        float* __restrict__ wout) {
    __shared__ float wg[S_];
    __shared__ float sbuf[4];
    int bh = blockIdx.x;
    int b = bh / H_;
    int t = threadIdx.x;

    float kv = k[(size_t)bh * M_ + t];
    float kn = sqrtf(block_sum(kv * kv, sbuf));

    float beta_v = beta[bh], g_v = g[bh], gam = gamma[bh];
    float s0 = sshift[bh * 3 + 0], s1 = sshift[bh * 3 + 1], s2 = sshift[bh * 3 + 2];

    float x[4];
    float mx = -INFINITY;
    #pragma unroll
    for (int j = 0; j < 4; ++j) {
        int sidx = t + 256 * j;
        float denom = fmaxf(kn * mn[(size_t)b * S_ + sidx], 1e-8f);
        float c = dots[(size_t)bh * S_ + sidx] / denom;
        x[j] = beta_v * c;
        mx = fmaxf(mx, x[j]);
    }
    mx = block_max(mx, sbuf);

    float e[4];
    float se = 0.f;
    #pragma unroll
    for (int j = 0; j < 4; ++j) { e[j] = __expf(x[j] - mx); se += e[j]; }
    se = block_sum(se, sbuf);
    float inv = 1.f / se;

    #pragma unroll
    for (int j = 0; j < 4; ++j) {
        int sidx = t + 256 * j;
        wg[sidx] = g_v * (e[j] * inv) + (1.f - g_v) * pw[(size_t)bh * S_ + sidx];
    }
    __syncthreads();

    // ws = 3-tap circular conv, then ^gamma via native base-2 exp/log
    float wgam[4];
    float tot = 0.f;
    #pragma unroll
    for (int j = 0; j < 4; ++j) {
        int sidx = t + 256 * j;
        float wsv = s0 * wg[(sidx + S_ - 1) & (S_ - 1)]
                  + s1 * wg[sidx]
                  + s2 * wg[(sidx + 1) & (S_ - 1)];
        float p = (wsv > 0.f) ? exp2f(gam * log2f(wsv)) : 0.f;
        wgam[j] = p;
        tot += p;
    }
    tot = block_sum(tot, sbuf);
    float invt = 1.f / tot;
    #pragma unroll
    for (int j = 0; j < 4; ++j) {
        int sidx = t + 256 * j;
        wout[(size_t)bh * S_ + sidx] = wgam[j] * invt;
    }
}

// ---------------- K3: nmem + partial r ----------------
// ROWS=64 so the bid->(b,rows) map matches K1 exactly (same XCD L2 reuse).
// NT load of memory (last use) + NT store of nmem (streaming output).
__global__ __launch_bounds__(256) void k3_write(
        const float* __restrict__ memory, const float* __restrict__ erase,
        const float* __restrict__ addv, const float* __restrict__ w,
        float* __restrict__ nmem, float* __restrict__ partial) {
    const int ROWS = 64, NCH = S_ / ROWS;
    int bid = blockIdx.x;
    int b = bid / NCH, ch = bid % NCH;
    int wave = threadIdx.x >> 6, lane = threadIdx.x & 63;

    __shared__ float wloc[H_][ROWS];
    __shared__ float rbuf[4][H_ * M_];   // 16 KB

    {
        int idx = threadIdx.x;           // 256 = H_*ROWS exactly
        int h = idx / ROWS, i = idx % ROWS;
        wloc[h][i] = w[((size_t)b * H_ + h) * S_ + ch * ROWS + i];
    }
    __syncthreads();

    float4 er = reinterpret_cast<const float4*>(
        erase + ((size_t)b * H_ + (H_ - 1)) * M_)[lane];
    float4 ad = reinterpret_cast<const float4*>(
        addv + ((size_t)b * H_ + (H_ - 1)) * M_)[lane];

    float4 racc[H_];
    #pragma unroll
    for (int h = 0; h < H_; ++h) racc[h] = make_float4(0.f, 0.f, 0.f, 0.f);

    #pragma unroll 4
    for (int i = 0; i < ROWS / 4; ++i) {
        int l = wave + 4 * i;
        int srow = ch * ROWS + l;
        vfloat4 m4 = __builtin_nontemporal_load(
            reinterpret_cast<const vfloat4*>(memory + ((size_t)b * S_ + srow) * M_) + lane);
        float wl = wloc[H_ - 1][l];
        vfloat4 nm;
        nm.x = m4.x * (1.f - wl * er.x) + wl * ad.x;
        nm.y = m4.y * (1.f - wl * er.y) + wl * ad.y;
        nm.z = m4.z * (1.f - wl * er.z) + wl * ad.z;
        nm.w = m4.w * (1.f - wl * er.w) + wl * ad.w;
        __builtin_nontemporal_store(nm,
            reinterpret_cast<vfloat4*>(nmem + ((size_t)b * S_ + srow) * M_) + lane);
        #pragma unroll
        for (int h = 0; h < H_; ++h) {
            float wh = wloc[h][l];
            racc[h].x += wh * nm.x;
            racc[h].y += wh * nm.y;
            racc[h].z += wh * nm.z;
            racc[h].w += wh * nm.w;
        }
    }

    #pragma unroll
    for (int h = 0; h < H_; ++h) {
        rbuf[wave][h * M_ + 4 * lane + 0] = racc[h].x;
        rbuf[wave][h * M_ + 4 * lane + 1] = racc[h].y;
        rbuf[wave][h * M_ + 4 * lane + 2] = racc[h].z;
        rbuf[wave][h * M_ + 4 * lane + 3] = racc[h].w;
    }
    __syncthreads();

    for (int idx = threadIdx.x; idx < H_ * M_; idx += 256) {
        float sum = rbuf[0][idx] + rbuf[1][idx] + rbuf[2][idx] + rbuf[3][idx];
        partial[((size_t)(b * NCH + ch)) * H_ * M_ + idx] = sum;
    }
}

// ---------------- K4: reduce partials -> r ----------------
__global__ __launch_bounds__(256) void k4_reduce(
        const float* __restrict__ partial, float* __restrict__ rout) {
    int idx = blockIdx.x * 256 + threadIdx.x;
    int b = idx / (H_ * M_);
    int hm = idx % (H_ * M_);
    float sum = 0.f;
    #pragma unroll
    for (int ch = 0; ch < 16; ++ch)
        sum += partial[((size_t)(b * 16 + ch)) * H_ * M_ + hm];
    rout[idx] = sum;
}

// ---------------- launch ----------------
extern "C" void kernel_launch(void* const* d_in, const int* in_sizes, int n_in,
                              void* d_out, int out_size, void* d_ws, size_t ws_size,
                              hipStream_t stream) {
    const float* memory = (const float*)d_in[0];
    const float* k      = (const float*)d_in[1];
    const float* beta   = (const float*)d_in[2];
    const float* pw     = (const float*)d_in[3];
    const float* g      = (const float*)d_in[4];
    const float* s      = (const float*)d_in[5];
    const float* gamma  = (const float*)d_in[6];
    const float* erase  = (const float*)d_in[7];
    const float* addv   = (const float*)d_in[8];

    float* out  = (float*)d_out;
    float* nmem = out;                               // B*S*M
    float* rout = out + (size_t)B_ * S_ * M_;        // B*H*M

    float* wsf     = (float*)d_ws;
    float* dots    = wsf;                                  // B*H*S
    float* mn      = dots + (size_t)B_ * H_ * S_;          // B*S
    float* wbuf    = mn + (size_t)B_ * S_;                 // B*H*S
    float* partial = wbuf + (size_t)B_ * H_ * S_;          // B*16*H*M

    k1_dots<<<B_ * (S_ / 64), 256, 0, stream>>>(memory, k, dots, mn);
    k2_weights<<<B_ * H_, 256, 0, stream>>>(k, beta, pw, g, s, gamma, dots, mn, wbuf);
    k3_write<<<B_ * (S_ / 64), 256, 0, stream>>>(memory, erase, addv, wbuf, nmem, partial);
    k4_reduce<<<(B_ * H_ * M_) / 256, 256, 0, stream>>>(partial, rout);
}

// Round 6
// 276.741 us; speedup vs baseline: 1.0037x; 1.0037x over previous
//
#include <hip/hip_runtime.h>
#include <math.h>

#define B_ 128
#define H_ 4
#define S_ 1024
#define M_ 256

typedef float vfloat4 __attribute__((ext_vector_type(4)));

// ---------------- helpers ----------------

__device__ __forceinline__ float wred_sum(float v) {
    #pragma unroll
    for (int o = 32; o; o >>= 1) v += __shfl_xor(v, o);
    return v;
}

__device__ __forceinline__ float wred_max(float v) {
    #pragma unroll
    for (int o = 32; o; o >>= 1) v = fmaxf(v, __shfl_xor(v, o));
    return v;
}

__device__ __forceinline__ float block_sum(float v, float* sbuf) {
    v = wred_sum(v);
    int wave = threadIdx.x >> 6, lane = threadIdx.x & 63;
    if (lane == 0) sbuf[wave] = v;
    __syncthreads();
    float r = sbuf[0] + sbuf[1] + sbuf[2] + sbuf[3];
    __syncthreads();
    return r;
}

__device__ __forceinline__ float block_max(float v, float* sbuf) {
    v = wred_max(v);
    int wave = threadIdx.x >> 6, lane = threadIdx.x & 63;
    if (lane == 0) sbuf[wave] = v;
    __syncthreads();
    float r = fmaxf(fmaxf(sbuf[0], sbuf[1]), fmaxf(sbuf[2], sbuf[3]));
    __syncthreads();
    return r;
}

// ---------------- K1: dots + row norms ----------------
// 16 lanes per row, 4 rows per wave-iter. grid: B*16 blocks, 64 rows/block.
__global__ __launch_bounds__(256) void k1_dots(
        const float* __restrict__ memory, const float* __restrict__ k,
        float* __restrict__ dots, float* __restrict__ mn) {
    const int RPB = 64;
    int bid = blockIdx.x;
    int b = bid / (S_ / RPB);
    int ch = bid % (S_ / RPB);
    int wave = threadIdx.x >> 6, lane = threadIdx.x & 63;
    int sub = lane & 15, rq = lane >> 4;

    float4 kf[H_][4];
    #pragma unroll
    for (int h = 0; h < H_; ++h)
        #pragma unroll
        for (int c = 0; c < 4; ++c)
            kf[h][c] = reinterpret_cast<const float4*>(
                k + ((size_t)b * H_ + h) * M_)[c * 16 + sub];

    #pragma unroll
    for (int i = 0; i < RPB / 16; ++i) {
        int s = ch * RPB + wave * 16 + i * 4 + rq;
        const float4* row = reinterpret_cast<const float4*>(
            memory + ((size_t)b * S_ + s) * M_);
        float d[H_] = {0.f, 0.f, 0.f, 0.f};
        float nn = 0.f;
        #pragma unroll
        for (int c = 0; c < 4; ++c) {
            float4 m4 = row[c * 16 + sub];
            #pragma unroll
            for (int h = 0; h < H_; ++h)
                d[h] += m4.x * kf[h][c].x + m4.y * kf[h][c].y
                      + m4.z * kf[h][c].z + m4.w * kf[h][c].w;
            nn += m4.x * m4.x + m4.y * m4.y + m4.z * m4.z + m4.w * m4.w;
        }
        #pragma unroll
        for (int o = 1; o < 16; o <<= 1) {
            #pragma unroll
            for (int h = 0; h < H_; ++h) d[h] += __shfl_xor(d[h], o);
            nn += __shfl_xor(nn, o);
        }
        if (sub == 0) {
            #pragma unroll
            for (int h = 0; h < H_; ++h)
                dots[((size_t)b * H_ + h) * S_ + s] = d[h];
            mn[(size_t)b * S_ + s] = sqrtf(nn);
        }
    }
}

// ---------------- K2: per-(b,h) weight pipeline ----------------
__global__ __launch_bounds__(256) void k2_weights(
        const float* __restrict__ k, const float* __restrict__ beta,
        const float* __restrict__ pw, const float* __restrict__ g,
        const float* __restrict__ sshift, const float* __restrict__ gamma,
        const float* __restrict__ dots, const float* __restrict__ mn,
        float* __restrict__ wout) {
    __shared__ float wg[S_];
    __shared__ float sbuf[4];
    int bh = blockIdx.x;
    int b = bh / H_;
    int t = threadIdx.x;

    float kv = k[(size_t)bh * M_ + t];
    float kn = sqrtf(block_sum(kv * kv, sbuf));

    float beta_v = beta[bh], g_v = g[bh], gam = gamma[bh];
    float s0 = sshift[bh * 3 + 0], s1 = sshift[bh * 3 + 1], s2 = sshift[bh * 3 + 2];

    float x[4];
    float mx = -INFINITY;
    #pragma unroll
    for (int j = 0; j < 4; ++j) {
        int sidx = t + 256 * j;
        float denom = fmaxf(kn * mn[(size_t)b * S_ + sidx], 1e-8f);
        float c = dots[(size_t)bh * S_ + sidx] / denom;
        x[j] = beta_v * c;
        mx = fmaxf(mx, x[j]);
    }
    mx = block_max(mx, sbuf);

    float e[4];
    float se = 0.f;
    #pragma unroll
    for (int j = 0; j < 4; ++j) { e[j] = __expf(x[j] - mx); se += e[j]; }
    se = block_sum(se, sbuf);
    float inv = 1.f / se;

    #pragma unroll
    for (int j = 0; j < 4; ++j) {
        int sidx = t + 256 * j;
        wg[sidx] = g_v * (e[j] * inv) + (1.f - g_v) * pw[(size_t)bh * S_ + sidx];
    }
    __syncthreads();

    float wgam[4];
    float tot = 0.f;
    #pragma unroll
    for (int j = 0; j < 4; ++j) {
        int sidx = t + 256 * j;
        float wsv = s0 * wg[(sidx + S_ - 1) & (S_ - 1)]
                  + s1 * wg[sidx]
                  + s2 * wg[(sidx + 1) & (S_ - 1)];
        float p = (wsv > 0.f) ? exp2f(gam * log2f(wsv)) : 0.f;
        wgam[j] = p;
        tot += p;
    }
    tot = block_sum(tot, sbuf);
    float invt = 1.f / tot;
    #pragma unroll
    for (int j = 0; j < 4; ++j) {
        int sidx = t + 256 * j;
        wout[(size_t)bh * S_ + sidx] = wgam[j] * invt;
    }
}

// ---------------- K3: nmem + partial r ----------------
// Reversed block order (LIFO vs K1's stream) so the most-recently cached
// L2/L3 lines from K1's pass are read first. Plain loads (deconfound R4's
// NT-load), NT stores for the streaming nmem output.
__global__ __launch_bounds__(256) void k3_write(
        const float* __restrict__ memory, const float* __restrict__ erase,
        const float* __restrict__ addv, const float* __restrict__ w,
        float* __restrict__ nmem, float* __restrict__ partial) {
    const int ROWS = 64, NCH = S_ / ROWS;
    int bid = (int)gridDim.x - 1 - (int)blockIdx.x;   // LIFO
    int b = bid / NCH, ch = bid % NCH;
    int wave = threadIdx.x >> 6, lane = threadIdx.x & 63;

    __shared__ float wloc[H_][ROWS];
    __shared__ float rbuf[4][H_ * M_];   // 16 KB

    {
        int idx = threadIdx.x;           // 256 = H_*ROWS exactly
        int h = idx / ROWS, i = idx % ROWS;
        wloc[h][i] = w[((size_t)b * H_ + h) * S_ + ch * ROWS + i];
    }
    __syncthreads();

    float4 er = reinterpret_cast<const float4*>(
        erase + ((size_t)b * H_ + (H_ - 1)) * M_)[lane];
    float4 ad = reinterpret_cast<const float4*>(
        addv + ((size_t)b * H_ + (H_ - 1)) * M_)[lane];

    float4 racc[H_];
    #pragma unroll
    for (int h = 0; h < H_; ++h) racc[h] = make_float4(0.f, 0.f, 0.f, 0.f);

    #pragma unroll 4
    for (int i = 0; i < ROWS / 4; ++i) {
        int l = wave + 4 * i;
        int srow = ch * ROWS + l;
        float4 m4 = reinterpret_cast<const float4*>(
            memory + ((size_t)b * S_ + srow) * M_)[lane];
        float wl = wloc[H_ - 1][l];
        vfloat4 nm;
        nm.x = m4.x * (1.f - wl * er.x) + wl * ad.x;
        nm.y = m4.y * (1.f - wl * er.y) + wl * ad.y;
        nm.z = m4.z * (1.f - wl * er.z) + wl * ad.z;
        nm.w = m4.w * (1.f - wl * er.w) + wl * ad.w;
        __builtin_nontemporal_store(nm,
            reinterpret_cast<vfloat4*>(nmem + ((size_t)b * S_ + srow) * M_) + lane);
        #pragma unroll
        for (int h = 0; h < H_; ++h) {
            float wh = wloc[h][l];
            racc[h].x += wh * nm.x;
            racc[h].y += wh * nm.y;
            racc[h].z += wh * nm.z;
            racc[h].w += wh * nm.w;
        }
    }

    #pragma unroll
    for (int h = 0; h < H_; ++h) {
        rbuf[wave][h * M_ + 4 * lane + 0] = racc[h].x;
        rbuf[wave][h * M_ + 4 * lane + 1] = racc[h].y;
        rbuf[wave][h * M_ + 4 * lane + 2] = racc[h].z;
        rbuf[wave][h * M_ + 4 * lane + 3] = racc[h].w;
    }
    __syncthreads();

    for (int idx = threadIdx.x; idx < H_ * M_; idx += 256) {
        float sum = rbuf[0][idx] + rbuf[1][idx] + rbuf[2][idx] + rbuf[3][idx];
        partial[((size_t)(b * NCH + ch)) * H_ * M_ + idx] = sum;
    }
}

// ---------------- K4: reduce partials -> r ----------------
__global__ __launch_bounds__(256) void k4_reduce(
        const float* __restrict__ partial, float* __restrict__ rout) {
    int idx = blockIdx.x * 256 + threadIdx.x;
    int b = idx / (H_ * M_);
    int hm = idx % (H_ * M_);
    float sum = 0.f;
    #pragma unroll
    for (int ch = 0; ch < 16; ++ch)
        sum += partial[((size_t)(b * 16 + ch)) * H_ * M_ + hm];
    rout[idx] = sum;
}

// ---------------- launch ----------------
extern "C" void kernel_launch(void* const* d_in, const int* in_sizes, int n_in,
                              void* d_out, int out_size, void* d_ws, size_t ws_size,
                              hipStream_t stream) {
    const float* memory = (const float*)d_in[0];
    const float* k      = (const float*)d_in[1];
    const float* beta   = (const float*)d_in[2];
    const float* pw     = (const float*)d_in[3];
    const float* g      = (const float*)d_in[4];
    const float* s      = (const float*)d_in[5];
    const float* gamma  = (const float*)d_in[6];
    const float* erase  = (const float*)d_in[7];
    const float* addv   = (const float*)d_in[8];

    float* out  = (float*)d_out;
    float* nmem = out;                               // B*S*M
    float* rout = out + (size_t)B_ * S_ * M_;        // B*H*M

    float* wsf     = (float*)d_ws;
    float* dots    = wsf;                                  // B*H*S
    float* mn      = dots + (size_t)B_ * H_ * S_;          // B*S
    float* wbuf    = mn + (size_t)B_ * S_;                 // B*H*S
    float* partial = wbuf + (size_t)B_ * H_ * S_;          // B*16*H*M

    k1_dots<<<B_ * (S_ / 64), 256, 0, stream>>>(memory, k, dots, mn);
    k2_weights<<<B_ * H_, 256, 0, stream>>>(k, beta, pw, g, s, gamma, dots, mn, wbuf);
    k3_write<<<B_ * (S_ / 64), 256, 0, stream>>>(memory, erase, addv, wbuf, nmem, partial);
    k4_reduce<<<(B_ * H_ * M_) / 256, 256, 0, stream>>>(partial, rout);
}